// Round 16
// baseline (78.852 us; speedup 1.0000x reference)
//
#include <hip/hip_runtime.h>
#include <hip/hip_bf16.h>

#define HH 256
#define WW 256
#define CC 3
#define KK 9
#define OC 64
#define KD 27
#define PSTS 40    // patch/D/S row stride in shorts (80 B) — proven 0-conflict b128 pattern
#define WRB 5120   // per-wave LDS bytes: 64 rows x 80B (D-tail packed in bytes 64..79)
#define NWAVES 8
#define XST (NWAVES * WRB)   // xstage offset in LDSBUF = 40960
#define XSLOT 1024           // shorts per staged slot (256 px * 4 shorts)
#define SLOTS 8              // staged rows: r0-3 .. r0+4

typedef __attribute__((ext_vector_type(8))) short bf16x8;
typedef __attribute__((ext_vector_type(4))) short s16x4;
typedef __attribute__((ext_vector_type(4))) float f32x4;
typedef __attribute__((ext_vector_type(2))) float f32x2;
typedef __attribute__((ext_vector_type(2))) unsigned int u32x2;
typedef __attribute__((ext_vector_type(4))) unsigned int u32x4;

// hardware RNE f32 -> bf16
static __device__ __forceinline__ short f2bf(float f) {
    __hip_bfloat16 h = __float2bfloat16(f);
    return __builtin_bit_cast(short, h);
}
static __device__ __forceinline__ unsigned pack2(short a, short b) {
    return (unsigned)(unsigned short)a | ((unsigned)(unsigned short)b << 16);
}
static __device__ __forceinline__ float bf2f(unsigned w) {   // low 16 bits
    return __uint_as_float(w << 16);
}
static __device__ __forceinline__ float bfup(unsigned w) {   // high 16 bits
    return __uint_as_float(w & 0xffff0000u);
}
static __device__ __forceinline__ unsigned q8(float z) {     // sigmoid -> u8
    float s = 1.0f / (1.0f + __expf(-z));
    return (unsigned)__builtin_rintf(s * 255.0f);
}

// ===================== prep: bf16 pixel-major x copy + weight fragments ========
__global__ __launch_bounds__(256) void dcn_prep(
    const float* __restrict__ x,
    const float* __restrict__ w_offset, const float* __restrict__ b_offset,
    const float* __restrict__ w_mask,   const float* __restrict__ b_mask,
    const float* __restrict__ w_conv,
    short* __restrict__ xbf, short* __restrict__ wcf, char* __restrict__ wof,
    int npix)
{
    const int tid = threadIdx.x;
    if (blockIdx.x == gridDim.x - 1) {
        if (tid < 64) {
            const int fm = tid & 15, kc = tid >> 4;
#pragma unroll
            for (int t = 0; t < 4; ++t) {
                bf16x8 v;
#pragma unroll
                for (int e = 0; e < 8; ++e) {
                    int kd = kc * 8 + e;
                    v[e] = (kd < KD) ? f2bf(w_conv[(t * 16 + fm) * KD + kd]) : (short)0;
                }
                *(bf16x8*)(wcf + tid * 32 + t * 8) = v;
            }
#pragma unroll
            for (int t = 0; t < 2; ++t) {
                int ch = t * 16 + fm;
                bf16x8 vh, vl;
#pragma unroll
                for (int e = 0; e < 8; ++e) {
                    int kd = kc * 8 + e;
                    float val = 0.0f;
                    if (kd < KD) {
                        if (ch < 18) val = w_offset[ch * KD + kd];
                        else if (ch < KD) val = w_mask[(ch - 18) * KD + kd];
                    }
                    unsigned u = __float_as_uint(val);
                    vh[e] = (short)(u >> 16);
                    float dd = val - __uint_as_float(u & 0xffff0000u);
                    vl[e] = (short)(__float_as_uint(dd) >> 16);
                }
                *(bf16x8*)(wof + tid * 96 + t * 16) = vh;
                *(bf16x8*)(wof + tid * 96 + 32 + t * 16) = vl;
            }
#pragma unroll
            for (int t = 0; t < 2; ++t) {
                f32x4 cb;
#pragma unroll
                for (int r = 0; r < 4; ++r) {
                    int ch = t * 16 + kc * 4 + r;
                    float v = 0.0f;
                    if (ch < 18) v = b_offset[ch];
                    else if (ch < KD) v = b_mask[ch - 18];
                    cb[r] = v;
                }
                *(f32x4*)(wof + tid * 96 + 64 + t * 16) = cb;
            }
        }
        return;
    }

    const int p0 = (blockIdx.x * 256 + tid) * 4;   // 4 consecutive pixels
    if (p0 >= npix) return;
    const int bb = p0 >> 16;
    const int q  = p0 & 0xffff;
    const float* xb = x + (size_t)bb * (3 * 65536) + q;
    f32x4 r0 = *(const f32x4*)(xb);
    f32x4 r1 = *(const f32x4*)(xb + 65536);
    f32x4 r2 = *(const f32x4*)(xb + 131072);

    bf16x8 v0 = {f2bf(r0[0]), f2bf(r1[0]), f2bf(r2[0]), 0,
                 f2bf(r0[1]), f2bf(r1[1]), f2bf(r2[1]), 0};
    bf16x8 v1 = {f2bf(r0[2]), f2bf(r1[2]), f2bf(r2[2]), 0,
                 f2bf(r0[3]), f2bf(r1[3]), f2bf(r2[3]), 0};
    short* A = xbf + (size_t)p0 * 4;
    *(bf16x8*)A       = v0;
    *(bf16x8*)(A + 8) = v1;
}

// ================================ main =========================================
// One block = 2 consecutive output rows, processed CONCURRENTLY: waves 0-3 do
// row r0, waves 4-7 do row r0+1. 57344 B LDS -> 2 blocks/CU = 16 waves/CU.
__global__ __launch_bounds__(512, 4) void dcn_main(
    const float* __restrict__ x,     // (B,3,256,256) f32 (slow-path only)
    const short* __restrict__ xbf,   // (B,H,W,4) bf16 pixel-major
    const short* __restrict__ wcf,
    const char*  __restrict__ wof,
    float* __restrict__ out)         // (B,64,256,256)
{
    __shared__ __align__(16) char LDSBUF[XST + SLOTS * XSLOT * 2];   // 40960+16384=57344

    const int tid = threadIdx.x;          // 0..511
    const int d = tid >> 8;               // row half: 0 or 1
    const int j = tid & 255;              // pixel column
    const int r0 = (blockIdx.x & 127) * 2;
    const int b = blockIdx.x >> 7;
    const int ri = r0 + d;
    const int lane = tid & 63;
    const int wv = tid >> 6;              // 0..7
    const int fm = lane & 15;
    const int kc = lane >> 4;

    char* wbase = LDSBUF + wv * WRB;
    short* patchS = (short*)wbase;
    short* xs = (short*)(LDSBUF + XST);   // [8 slots][256 px][4 shorts] bf16

    const float* xb = x + (size_t)b * (CC * HH * WW);
    const short* xrow = xbf + (size_t)b * (HH * WW * 4);

    // ---- phase 0: stage rows r0-3 .. r0+4 (clamped); each thread does 4 slots ----
    {
        u32x2 st[4];
#pragma unroll
        for (int s = 0; s < 4; ++s) {
            int slot = d * 4 + s;
            int gr = min(max(r0 - 3 + slot, 0), HH - 1);
            st[s] = *(const u32x2*)(xrow + ((size_t)gr * WW + j) * 4);
        }
#pragma unroll
        for (int s = 0; s < 4; ++s) {
            *(u32x2*)(xs + (d * 4 + s) * XSLOT + j * 4) = st[s];
        }
    }
    __syncthreads();

    // ---- conv W fragments + bias ----
    const char* wl = wof + lane * 96;
    bf16x8 whi0 = *(const bf16x8*)(wl);
    bf16x8 whi1 = *(const bf16x8*)(wl + 16);
    bf16x8 wlo0 = *(const bf16x8*)(wl + 32);
    bf16x8 wlo1 = *(const bf16x8*)(wl + 48);
    f32x4 cb0 = *(const f32x4*)(wl + 64);
    f32x4 cb1 = *(const f32x4*)(wl + 80);
    bf16x8 afrag[4];
#pragma unroll
    for (int t2 = 0; t2 < 4; ++t2) afrag[t2] = *(const bf16x8*)(wcf + lane * 32 + t2 * 8);

    const float* x0p = xb;
    const float* x1p = xb + (size_t)HH * WW;
    const float* x2p = xb + (size_t)2 * HH * WW;

    // ---- patch from LDS (9 b64 reads), zero-padded at image borders ----
    {
        const bool yok0 = (ri - 1) >= 0, yok2 = (ri + 1) < HH;
        const bool xok0 = (j - 1) >= 0, xok2 = (j + 1) < WW;
        s16x4 pr[3][3];
#pragma unroll
        for (int p = 0; p < 3; ++p) {
#pragma unroll
            for (int q = 0; q < 3; ++q) {
                int xx = min(max(j + q - 1, 0), WW - 1);
                pr[p][q] = *(const s16x4*)(xs + (d + p + 2) * XSLOT + xx * 4);
            }
        }
        short* rp = patchS + lane * PSTS;
#pragma unroll
        for (int o = 0; o < 4; ++o) {
            bf16x8 vh;
#pragma unroll
            for (int e = 0; e < 8; ++e) {
                int kd = o * 8 + e;
                if (kd < KD) {
                    int c = kd / 9, rem = kd - c * 9, p = rem / 3, q = rem - p * 3;
                    bool ok = (p == 0 ? yok0 : (p == 2 ? yok2 : true)) &&
                              (q == 0 ? xok0 : (q == 2 ? xok2 : true));
                    vh[e] = ok ? pr[p][q][c] : (short)0;
                } else {
                    vh[e] = (short)0;
                }
            }
            *(bf16x8*)(rp + o * 8) = vh;
        }
    }

    // ---- conv MFMA: D[32ch][64px] = (Whi+Wlo)*Phi + bias ----
    f32x4 dacc[4][2];
#pragma unroll
    for (int g = 0; g < 4; ++g) {
        bf16x8 phi = *(const bf16x8*)(patchS + (g * 16 + fm) * PSTS + kc * 8);
        f32x4 a0 = __builtin_amdgcn_mfma_f32_16x16x32_bf16(whi0, phi, cb0, 0, 0, 0);
        a0 = __builtin_amdgcn_mfma_f32_16x16x32_bf16(wlo0, phi, a0, 0, 0, 0);
        f32x4 a1 = __builtin_amdgcn_mfma_f32_16x16x32_bf16(whi1, phi, cb1, 0, 0, 0);
        a1 = __builtin_amdgcn_mfma_f32_16x16x32_bf16(wlo1, phi, a1, 0, 0, 0);
        dacc[g][0] = a0;
        dacc[g][1] = a1;
    }
    // D rows (80 B): 16 f32 dy/dx (k0..7) @0..63; tail @64: dy8dx8 bf16 (4B),
    // m0..m8 u8 @68..76 (sigmoid applied at write time)
#pragma unroll
    for (int g = 0; g < 4; ++g) {
        int r = g * 16 + fm;
        char* dr = wbase + r * 80;
        *(f32x4*)(dr + kc * 16) = dacc[g][0];
        f32x4 a1 = dacc[g][1];
        if (kc == 0) {          // ch16..19 = dy8, dx8, z0, z1
            *(unsigned*)(dr + 64) = pack2(f2bf(a1[0]), f2bf(a1[1]));
            *(unsigned short*)(dr + 68) = (unsigned short)(q8(a1[2]) | (q8(a1[3]) << 8));
        } else if (kc == 1) {   // ch20..23 = z2..z5
            *(unsigned short*)(dr + 70) = (unsigned short)(q8(a1[0]) | (q8(a1[1]) << 8));
            *(unsigned short*)(dr + 72) = (unsigned short)(q8(a1[2]) | (q8(a1[3]) << 8));
        } else if (kc == 2) {   // ch24..26 = z6..z8
            *(unsigned short*)(dr + 74) = (unsigned short)(q8(a1[0]) | (q8(a1[1]) << 8));
            *(unsigned short*)(dr + 76) = (unsigned short)q8(a1[2]);
        }
    }

    // ---- read own D row fully (before S overwrites region) ----
    const char* myD = wbase + lane * 80;
    f32x4 d03 = *(const f32x4*)(myD);
    f32x4 d47 = *(const f32x4*)(myD + 16);
    f32x4 d8b = *(const f32x4*)(myD + 32);
    f32x4 dcf = *(const f32x4*)(myD + 48);
    u32x4 tail = *(const u32x4*)(myD + 64);   // dy8dx8 | m0..m3 | m4..m7 | m8

    const float dyv[9] = {d03[0], d03[2], d47[0], d47[2], d8b[0], d8b[2], dcf[0], dcf[2],
                          bf2f(tail.x)};
    const float dxv[9] = {d03[1], d03[3], d47[1], d47[3], d8b[1], d8b[3], dcf[1], dcf[3],
                          bfup(tail.x)};
    const unsigned mqv[9] = {tail.y & 255u, (tail.y >> 8) & 255u, (tail.y >> 16) & 255u,
                             tail.y >> 24, tail.z & 255u, (tail.z >> 8) & 255u,
                             (tail.z >> 16) & 255u, tail.z >> 24, tail.w & 255u};

    // ---- sampling: px-major bf16 LDS reads (fast) with rare global fallback ----
    float s27[KD];
#pragma unroll
    for (int k = 0; k < KK; ++k) {
        float dy = dyv[k], dx = dxv[k];
        float msk = (float)mqv[k] * (1.0f / 255.0f);

        float py = (float)(ri + (k / 3) - 1) + dy;
        float px = (float)(j + (k % 3) - 1) + dx;
        float y0f = floorf(py), x0f = floorf(px);
        float wy = py - y0f, wx = px - x0f;
        int y0 = (int)y0f, x0 = (int)x0f;
        int y1 = y0 + 1, x1 = x0 + 1;

        float w00 = (1.0f - wy) * (1.0f - wx);
        float w01 = (1.0f - wy) * wx;
        float w10 = wy * (1.0f - wx);
        float w11 = wy * wx;

        bool v0y = (unsigned)y0 < HH, v1y = (unsigned)y1 < HH;
        bool v0x = (unsigned)x0 < WW, v1x = (unsigned)x1 < WW;
        float f00 = (v0y && v0x) ? w00 : 0.0f;
        float f01 = (v0y && v1x) ? w01 : 0.0f;
        float f10 = (v1y && v0x) ? w10 : 0.0f;
        float f11 = (v1y && v1x) ? w11 : 0.0f;

        int y0c = min(max(y0, 0), HH - 1), y1c = min(max(y1, 0), HH - 1);
        int s0 = y0c - r0 + 3;       // slot index, valid 0..7
        int s1 = y1c - r0 + 3;
        float r0v_, r1v_, r2v_;
        if (__builtin_expect(__any(((unsigned)s0 > (SLOTS - 1)) ||
                                   ((unsigned)s1 > (SLOTS - 1))), 0)) {
            // ---- slow path: global f32 gather (exact semantics) ----
            int x0c = min(max(x0, 0), WW - 1), x1c = min(max(x1, 0), WW - 1);
            int o00 = y0c * WW + x0c, o01 = y0c * WW + x1c;
            int o10 = y1c * WW + x0c, o11 = y1c * WW + x1c;
            r0v_ = x0p[o00] * f00 + x0p[o01] * f01 + x0p[o10] * f10 + x0p[o11] * f11;
            r1v_ = x1p[o00] * f00 + x1p[o01] * f01 + x1p[o10] * f10 + x1p[o11] * f11;
            r2v_ = x2p[o00] * f00 + x2p[o01] * f01 + x2p[o10] * f10 + x2p[o11] * f11;
        } else {
            // ---- fast path: 4 x 8B LDS reads; clamped-x handled by weight swap ----
            int xl = min(max(x0, 0), WW - 2);
            bool sw = (x0 != xl);
            const short* p0 = xs + s0 * XSLOT + xl * 4;
            const short* p1 = xs + s1 * XSLOT + xl * 4;
            u32x2 lo0 = *(const u32x2*)p0;
            u32x2 hi0 = *(const u32x2*)(p0 + 4);
            u32x2 lo1 = *(const u32x2*)p1;
            u32x2 hi1 = *(const u32x2*)(p1 + 4);

            float a0 = sw ? f01 : f00, b0 = sw ? f00 : f01;
            float a1w = sw ? f11 : f10, b1w = sw ? f10 : f11;

            r0v_ = fmaf(bf2f(lo0.x), a0, fmaf(bf2f(hi0.x), b0,
                   fmaf(bf2f(lo1.x), a1w, bf2f(hi1.x) * b1w)));
            r1v_ = fmaf(bfup(lo0.x), a0, fmaf(bfup(hi0.x), b0,
                   fmaf(bfup(lo1.x), a1w, bfup(hi1.x) * b1w)));
            r2v_ = fmaf(bf2f(lo0.y), a0, fmaf(bf2f(hi0.y), b0,
                   fmaf(bf2f(lo1.y), a1w, bf2f(hi1.y) * b1w)));
        }
        s27[k]      = r0v_ * msk;
        s27[9 + k]  = r1v_ * msk;
        s27[18 + k] = r2v_ * msk;
    }

    // ---- S rows: stride-80 b128 writes ----
    {
        short* srow = patchS + lane * PSTS;
#pragma unroll
        for (int o = 0; o < 4; ++o) {
            bf16x8 v;
#pragma unroll
            for (int e = 0; e < 8; ++e) {
                int kd = o * 8 + e;
                v[e] = (kd < KD) ? f2bf(s27[kd]) : (short)0;
            }
            *(bf16x8*)(srow + o * 8) = v;
        }
    }

    // ---- MFMA epilogue, operand-swapped: 4 consecutive px per lane ----
    float* obase = out + ((size_t)b * OC * HH + ri) * WW;
#pragma unroll
    for (int g = 0; g < 4; ++g) {
        bf16x8 sfrag = *(const bf16x8*)(patchS + (g * 16 + fm) * PSTS + kc * 8);
#pragma unroll
        for (int t2 = 0; t2 < 4; ++t2) {
            f32x4 acc = (f32x4){0.f, 0.f, 0.f, 0.f};
            acc = __builtin_amdgcn_mfma_f32_16x16x32_bf16(sfrag, afrag[t2], acc, 0, 0, 0);
            float* op = obase + (size_t)(t2 * 16 + fm) * (HH * WW) + ((wv & 3) * 64 + g * 16 + kc * 4);
            *(f32x4*)op = acc;
        }
    }
}

extern "C" void kernel_launch(void* const* d_in, const int* in_sizes, int n_in,
                              void* d_out, int out_size, void* d_ws, size_t ws_size,
                              hipStream_t stream) {
    const float* x        = (const float*)d_in[0];
    const float* w_offset = (const float*)d_in[1];
    const float* b_offset = (const float*)d_in[2];
    const float* w_mask   = (const float*)d_in[3];
    const float* b_mask   = (const float*)d_in[4];
    const float* w_conv   = (const float*)d_in[5];
    float* out = (float*)d_out;

    int B = in_sizes[0] / (CC * HH * WW);   // 16
    int npix = B * HH * WW;                 // 1,048,576

    // ws layout: xbf (npix*8 B) | wcf 4096 B | wof 6144 B
    short* xbf = (short*)d_ws;
    short* wcf = (short*)((char*)d_ws + (size_t)npix * 8);
    char*  wof = (char*)d_ws + (size_t)npix * 8 + 4096;

    int nb = (npix + 1023) / 1024;          // 4 px per thread
    hipLaunchKernelGGL(dcn_prep, dim3(nb + 1), dim3(256), 0, stream,
                       x, w_offset, b_offset, w_mask, b_mask, w_conv,
                       xbf, wcf, wof, npix);
    hipLaunchKernelGGL(dcn_main, dim3(B * (HH / 2)), dim3(512), 0, stream,
                       x, xbf, wcf, wof, out);
}

// Round 17
// 71.894 us; speedup vs baseline: 1.0968x; 1.0968x over previous
//
#include <hip/hip_runtime.h>
#include <hip/hip_bf16.h>

#define HH 256
#define WW 256
#define CC 3
#define KK 9
#define OC 64
#define KD 27
#define PSTS 40    // patch/D/S row stride in shorts (80 B) — proven 0-conflict b128 pattern
#define WRB 5120   // per-wave LDS bytes: 64 rows x 80B (D-tail packed in bytes 64..79)
#define XST (4 * WRB)   // xstage offset in LDSBUF = 20480
#define XSLOT 1024      // shorts per staged slot (256 px * 4 shorts)
#define ROWS 2          // output rows per block
#define SLOTS 8         // staged rows: r0-3 .. r0+4

typedef __attribute__((ext_vector_type(8))) short bf16x8;
typedef __attribute__((ext_vector_type(4))) short s16x4;
typedef __attribute__((ext_vector_type(4))) float f32x4;
typedef __attribute__((ext_vector_type(2))) float f32x2;
typedef __attribute__((ext_vector_type(2))) unsigned int u32x2;
typedef __attribute__((ext_vector_type(4))) unsigned int u32x4;

// hardware RNE f32 -> bf16
static __device__ __forceinline__ short f2bf(float f) {
    __hip_bfloat16 h = __float2bfloat16(f);
    return __builtin_bit_cast(short, h);
}
static __device__ __forceinline__ unsigned pack2(short a, short b) {
    return (unsigned)(unsigned short)a | ((unsigned)(unsigned short)b << 16);
}
static __device__ __forceinline__ float bf2f(unsigned w) {   // low 16 bits
    return __uint_as_float(w << 16);
}
static __device__ __forceinline__ float bfup(unsigned w) {   // high 16 bits
    return __uint_as_float(w & 0xffff0000u);
}
static __device__ __forceinline__ unsigned q8(float z) {     // sigmoid -> u8
    float s = 1.0f / (1.0f + __expf(-z));
    return (unsigned)__builtin_rintf(s * 255.0f);
}

// ===================== prep: bf16 pixel-major x copy + weight fragments ========
__global__ __launch_bounds__(256) void dcn_prep(
    const float* __restrict__ x,
    const float* __restrict__ w_offset, const float* __restrict__ b_offset,
    const float* __restrict__ w_mask,   const float* __restrict__ b_mask,
    const float* __restrict__ w_conv,
    short* __restrict__ xbf, short* __restrict__ wcf, char* __restrict__ wof,
    int npix)
{
    const int tid = threadIdx.x;
    if (blockIdx.x == gridDim.x - 1) {
        if (tid < 64) {
            const int fm = tid & 15, kc = tid >> 4;
#pragma unroll
            for (int t = 0; t < 4; ++t) {
                bf16x8 v;
#pragma unroll
                for (int e = 0; e < 8; ++e) {
                    int kd = kc * 8 + e;
                    v[e] = (kd < KD) ? f2bf(w_conv[(t * 16 + fm) * KD + kd]) : (short)0;
                }
                *(bf16x8*)(wcf + tid * 32 + t * 8) = v;
            }
#pragma unroll
            for (int t = 0; t < 2; ++t) {
                int ch = t * 16 + fm;
                bf16x8 vh, vl;
#pragma unroll
                for (int e = 0; e < 8; ++e) {
                    int kd = kc * 8 + e;
                    float val = 0.0f;
                    if (kd < KD) {
                        if (ch < 18) val = w_offset[ch * KD + kd];
                        else if (ch < KD) val = w_mask[(ch - 18) * KD + kd];
                    }
                    unsigned u = __float_as_uint(val);
                    vh[e] = (short)(u >> 16);
                    float d = val - __uint_as_float(u & 0xffff0000u);
                    vl[e] = (short)(__float_as_uint(d) >> 16);
                }
                *(bf16x8*)(wof + tid * 96 + t * 16) = vh;
                *(bf16x8*)(wof + tid * 96 + 32 + t * 16) = vl;
            }
#pragma unroll
            for (int t = 0; t < 2; ++t) {
                f32x4 cb;
#pragma unroll
                for (int r = 0; r < 4; ++r) {
                    int ch = t * 16 + kc * 4 + r;
                    float v = 0.0f;
                    if (ch < 18) v = b_offset[ch];
                    else if (ch < KD) v = b_mask[ch - 18];
                    cb[r] = v;
                }
                *(f32x4*)(wof + tid * 96 + 64 + t * 16) = cb;
            }
        }
        return;
    }

    const int p0 = (blockIdx.x * 256 + tid) * 4;   // 4 consecutive pixels
    if (p0 >= npix) return;
    const int bb = p0 >> 16;
    const int q  = p0 & 0xffff;
    const float* xb = x + (size_t)bb * (3 * 65536) + q;
    f32x4 r0 = *(const f32x4*)(xb);
    f32x4 r1 = *(const f32x4*)(xb + 65536);
    f32x4 r2 = *(const f32x4*)(xb + 131072);

    bf16x8 v0 = {f2bf(r0[0]), f2bf(r1[0]), f2bf(r2[0]), 0,
                 f2bf(r0[1]), f2bf(r1[1]), f2bf(r2[1]), 0};
    bf16x8 v1 = {f2bf(r0[2]), f2bf(r1[2]), f2bf(r2[2]), 0,
                 f2bf(r0[3]), f2bf(r1[3]), f2bf(r2[3]), 0};
    short* A = xbf + (size_t)p0 * 4;
    *(bf16x8*)A       = v0;
    *(bf16x8*)(A + 8) = v1;
}

// ================================ main =========================================
// One block = 2 consecutive output rows of one image. 36864 B LDS -> 4 blk/CU.
__global__ __launch_bounds__(256, 4) void dcn_main(
    const float* __restrict__ x,     // (B,3,256,256) f32 (slow-path only)
    const short* __restrict__ xbf,   // (B,H,W,4) bf16 pixel-major
    const short* __restrict__ wcf,
    const char*  __restrict__ wof,
    float* __restrict__ out)         // (B,64,256,256)
{
    __shared__ __align__(16) char LDSBUF[XST + SLOTS * XSLOT * 2];   // 20480+16384=36864

    const int tid = threadIdx.x;
    const int j = tid;
    const int r0 = (blockIdx.x & 127) * ROWS;
    const int b = blockIdx.x >> 7;
    const int lane = tid & 63;
    const int wv = tid >> 6;
    const int fm = lane & 15;
    const int kc = lane >> 4;

    char* wbase = LDSBUF + wv * WRB;
    short* patchS = (short*)wbase;
    short* xs = (short*)(LDSBUF + XST);   // [8 slots][256 px][4 shorts] bf16

    const float* xb = x + (size_t)b * (CC * HH * WW);
    const short* xrow = xbf + (size_t)b * (HH * WW * 4);

    // ---- phase 0: stage rows r0-3 .. r0+4 (clamped) from prepacked bf16 ----
    {
        u32x2 st[SLOTS];
#pragma unroll
        for (int s = 0; s < SLOTS; ++s) {
            int gr = min(max(r0 - 3 + s, 0), HH - 1);
            st[s] = *(const u32x2*)(xrow + ((size_t)gr * WW + tid) * 4);
        }
#pragma unroll
        for (int s = 0; s < SLOTS; ++s) {
            *(u32x2*)(xs + s * XSLOT + tid * 4) = st[s];
        }
    }
    __syncthreads();

    // ---- conv W fragments + bias (loaded once) ----
    const char* wl = wof + lane * 96;
    bf16x8 whi0 = *(const bf16x8*)(wl);
    bf16x8 whi1 = *(const bf16x8*)(wl + 16);
    bf16x8 wlo0 = *(const bf16x8*)(wl + 32);
    bf16x8 wlo1 = *(const bf16x8*)(wl + 48);
    f32x4 cb0 = *(const f32x4*)(wl + 64);
    f32x4 cb1 = *(const f32x4*)(wl + 80);
    bf16x8 afrag[4];
#pragma unroll
    for (int t2 = 0; t2 < 4; ++t2) afrag[t2] = *(const bf16x8*)(wcf + lane * 32 + t2 * 8);

    const float* x0p = xb;
    const float* x1p = xb + (size_t)HH * WW;
    const float* x2p = xb + (size_t)2 * HH * WW;

#pragma unroll 1
    for (int d = 0; d < ROWS; ++d) {
        const int ri = r0 + d;

        // ---- patch from LDS (9 b64 reads), zero-padded at image borders ----
        const bool yok0 = (ri - 1) >= 0, yok2 = (ri + 1) < HH;
        const bool xok0 = (j - 1) >= 0, xok2 = (j + 1) < WW;
        s16x4 pr[3][3];
#pragma unroll
        for (int p = 0; p < 3; ++p) {
#pragma unroll
            for (int q = 0; q < 3; ++q) {
                int xx = min(max(j + q - 1, 0), WW - 1);
                pr[p][q] = *(const s16x4*)(xs + (d + p + 2) * XSLOT + xx * 4);
            }
        }
        {
            short* rp = patchS + lane * PSTS;
#pragma unroll
            for (int o = 0; o < 4; ++o) {
                bf16x8 vh;
#pragma unroll
                for (int e = 0; e < 8; ++e) {
                    int kd = o * 8 + e;
                    if (kd < KD) {
                        int c = kd / 9, rem = kd - c * 9, p = rem / 3, q = rem - p * 3;
                        bool ok = (p == 0 ? yok0 : (p == 2 ? yok2 : true)) &&
                                  (q == 0 ? xok0 : (q == 2 ? xok2 : true));
                        vh[e] = ok ? pr[p][q][c] : (short)0;
                    } else {
                        vh[e] = (short)0;
                    }
                }
                *(bf16x8*)(rp + o * 8) = vh;
            }
        }

        // ---- conv MFMA: D[32ch][64px] = (Whi+Wlo)*Phi + bias ----
        f32x4 dacc[4][2];
#pragma unroll
        for (int g = 0; g < 4; ++g) {
            bf16x8 phi = *(const bf16x8*)(patchS + (g * 16 + fm) * PSTS + kc * 8);
            f32x4 a0 = __builtin_amdgcn_mfma_f32_16x16x32_bf16(whi0, phi, cb0, 0, 0, 0);
            a0 = __builtin_amdgcn_mfma_f32_16x16x32_bf16(wlo0, phi, a0, 0, 0, 0);
            f32x4 a1 = __builtin_amdgcn_mfma_f32_16x16x32_bf16(whi1, phi, cb1, 0, 0, 0);
            a1 = __builtin_amdgcn_mfma_f32_16x16x32_bf16(wlo1, phi, a1, 0, 0, 0);
            dacc[g][0] = a0;
            dacc[g][1] = a1;
        }
        // D rows (80 B): 16 f32 dy/dx (k0..7) @0..63; tail @64: dy8dx8 bf16 (4B),
        // m0..m8 u8 @68..76 (sigmoid applied at write time)
#pragma unroll
        for (int g = 0; g < 4; ++g) {
            int r = g * 16 + fm;
            char* dr = wbase + r * 80;
            *(f32x4*)(dr + kc * 16) = dacc[g][0];
            f32x4 a1 = dacc[g][1];
            if (kc == 0) {          // ch16..19 = dy8, dx8, z0, z1
                *(unsigned*)(dr + 64) = pack2(f2bf(a1[0]), f2bf(a1[1]));
                *(unsigned short*)(dr + 68) = (unsigned short)(q8(a1[2]) | (q8(a1[3]) << 8));
            } else if (kc == 1) {   // ch20..23 = z2..z5
                *(unsigned short*)(dr + 70) = (unsigned short)(q8(a1[0]) | (q8(a1[1]) << 8));
                *(unsigned short*)(dr + 72) = (unsigned short)(q8(a1[2]) | (q8(a1[3]) << 8));
            } else if (kc == 2) {   // ch24..26 = z6..z8
                *(unsigned short*)(dr + 74) = (unsigned short)(q8(a1[0]) | (q8(a1[1]) << 8));
                *(unsigned short*)(dr + 76) = (unsigned short)q8(a1[2]);
            }
        }

        // ---- read own D row fully (before S overwrites region) ----
        const char* myD = wbase + lane * 80;
        f32x4 d03 = *(const f32x4*)(myD);
        f32x4 d47 = *(const f32x4*)(myD + 16);
        f32x4 d8b = *(const f32x4*)(myD + 32);
        f32x4 dcf = *(const f32x4*)(myD + 48);
        u32x4 tail = *(const u32x4*)(myD + 64);   // dy8dx8 | m0..m3 | m4..m7 | m8

        const float dyv[9] = {d03[0], d03[2], d47[0], d47[2], d8b[0], d8b[2], dcf[0], dcf[2],
                              bf2f(tail.x)};
        const float dxv[9] = {d03[1], d03[3], d47[1], d47[3], d8b[1], d8b[3], dcf[1], dcf[3],
                              bfup(tail.x)};
        const unsigned mqv[9] = {tail.y & 255u, (tail.y >> 8) & 255u, (tail.y >> 16) & 255u,
                                 tail.y >> 24, tail.z & 255u, (tail.z >> 8) & 255u,
                                 (tail.z >> 16) & 255u, tail.z >> 24, tail.w & 255u};

        // ---- sampling: px-major bf16 LDS reads (fast) with rare global fallback ----
        float s27[KD];
#pragma unroll
        for (int k = 0; k < KK; ++k) {
            float dy = dyv[k], dx = dxv[k];
            float msk = (float)mqv[k] * (1.0f / 255.0f);

            float py = (float)(ri + (k / 3) - 1) + dy;
            float px = (float)(j + (k % 3) - 1) + dx;
            float y0f = floorf(py), x0f = floorf(px);
            float wy = py - y0f, wx = px - x0f;
            int y0 = (int)y0f, x0 = (int)x0f;
            int y1 = y0 + 1, x1 = x0 + 1;

            float w00 = (1.0f - wy) * (1.0f - wx);
            float w01 = (1.0f - wy) * wx;
            float w10 = wy * (1.0f - wx);
            float w11 = wy * wx;

            bool v0y = (unsigned)y0 < HH, v1y = (unsigned)y1 < HH;
            bool v0x = (unsigned)x0 < WW, v1x = (unsigned)x1 < WW;
            float f00 = (v0y && v0x) ? w00 : 0.0f;
            float f01 = (v0y && v1x) ? w01 : 0.0f;
            float f10 = (v1y && v0x) ? w10 : 0.0f;
            float f11 = (v1y && v1x) ? w11 : 0.0f;

            int y0c = min(max(y0, 0), HH - 1), y1c = min(max(y1, 0), HH - 1);
            int s0 = y0c - r0 + 3;       // slot index, valid 0..7
            int s1 = y1c - r0 + 3;
            float r0v_, r1v_, r2v_;
            if (__builtin_expect(__any(((unsigned)s0 > (SLOTS - 1)) ||
                                       ((unsigned)s1 > (SLOTS - 1))), 0)) {
                // ---- slow path: global f32 gather (exact semantics) ----
                int x0c = min(max(x0, 0), WW - 1), x1c = min(max(x1, 0), WW - 1);
                int o00 = y0c * WW + x0c, o01 = y0c * WW + x1c;
                int o10 = y1c * WW + x0c, o11 = y1c * WW + x1c;
                r0v_ = x0p[o00] * f00 + x0p[o01] * f01 + x0p[o10] * f10 + x0p[o11] * f11;
                r1v_ = x1p[o00] * f00 + x1p[o01] * f01 + x1p[o10] * f10 + x1p[o11] * f11;
                r2v_ = x2p[o00] * f00 + x2p[o01] * f01 + x2p[o10] * f10 + x2p[o11] * f11;
            } else {
                // ---- fast path: 4 x 8B LDS reads; clamped-x handled by weight swap ----
                int xl = min(max(x0, 0), WW - 2);
                bool sw = (x0 != xl);
                const short* p0 = xs + s0 * XSLOT + xl * 4;
                const short* p1 = xs + s1 * XSLOT + xl * 4;
                u32x2 lo0 = *(const u32x2*)p0;
                u32x2 hi0 = *(const u32x2*)(p0 + 4);
                u32x2 lo1 = *(const u32x2*)p1;
                u32x2 hi1 = *(const u32x2*)(p1 + 4);

                float a0 = sw ? f01 : f00, b0 = sw ? f00 : f01;
                float a1w = sw ? f11 : f10, b1w = sw ? f10 : f11;

                r0v_ = fmaf(bf2f(lo0.x), a0, fmaf(bf2f(hi0.x), b0,
                       fmaf(bf2f(lo1.x), a1w, bf2f(hi1.x) * b1w)));
                r1v_ = fmaf(bfup(lo0.x), a0, fmaf(bfup(hi0.x), b0,
                       fmaf(bfup(lo1.x), a1w, bfup(hi1.x) * b1w)));
                r2v_ = fmaf(bf2f(lo0.y), a0, fmaf(bf2f(hi0.y), b0,
                       fmaf(bf2f(lo1.y), a1w, bf2f(hi1.y) * b1w)));
            }
            s27[k]      = r0v_ * msk;
            s27[9 + k]  = r1v_ * msk;
            s27[18 + k] = r2v_ * msk;
        }

        // ---- S rows: stride-80 b128 writes ----
        {
            short* srow = patchS + lane * PSTS;
#pragma unroll
            for (int o = 0; o < 4; ++o) {
                bf16x8 v;
#pragma unroll
                for (int e = 0; e < 8; ++e) {
                    int kd = o * 8 + e;
                    v[e] = (kd < KD) ? f2bf(s27[kd]) : (short)0;
                }
                *(bf16x8*)(srow + o * 8) = v;
            }
        }

        // ---- MFMA epilogue, operand-swapped: 4 consecutive px per lane ----
        float* obase = out + ((size_t)b * OC * HH + ri) * WW;
#pragma unroll
        for (int g = 0; g < 4; ++g) {
            bf16x8 sfrag = *(const bf16x8*)(patchS + (g * 16 + fm) * PSTS + kc * 8);
#pragma unroll
            for (int t2 = 0; t2 < 4; ++t2) {
                f32x4 acc = (f32x4){0.f, 0.f, 0.f, 0.f};
                acc = __builtin_amdgcn_mfma_f32_16x16x32_bf16(sfrag, afrag[t2], acc, 0, 0, 0);
                float* op = obase + (size_t)(t2 * 16 + fm) * (HH * WW) + (wv * 64 + g * 16 + kc * 4);
                *(f32x4*)op = acc;
            }
        }
    }
}

extern "C" void kernel_launch(void* const* d_in, const int* in_sizes, int n_in,
                              void* d_out, int out_size, void* d_ws, size_t ws_size,
                              hipStream_t stream) {
    const float* x        = (const float*)d_in[0];
    const float* w_offset = (const float*)d_in[1];
    const float* b_offset = (const float*)d_in[2];
    const float* w_mask   = (const float*)d_in[3];
    const float* b_mask   = (const float*)d_in[4];
    const float* w_conv   = (const float*)d_in[5];
    float* out = (float*)d_out;

    int B = in_sizes[0] / (CC * HH * WW);   // 16
    int npix = B * HH * WW;                 // 1,048,576

    // ws layout: xbf (npix*8 B) | wcf 4096 B | wof 6144 B
    short* xbf = (short*)d_ws;
    short* wcf = (short*)((char*)d_ws + (size_t)npix * 8);
    char*  wof = (char*)d_ws + (size_t)npix * 8 + 4096;

    int nb = (npix + 1023) / 1024;          // 4 px per thread
    hipLaunchKernelGGL(dcn_prep, dim3(nb + 1), dim3(256), 0, stream,
                       x, w_offset, b_offset, w_mask, b_mask, w_conv,
                       xbf, wcf, wof, npix);
    hipLaunchKernelGGL(dcn_main, dim3(B * (HH / ROWS)), dim3(256), 0, stream,
                       x, xbf, wcf, wof, out);
}

// Round 18
// 70.550 us; speedup vs baseline: 1.1177x; 1.0191x over previous
//
#include <hip/hip_runtime.h>
#include <hip/hip_bf16.h>

#define HH 256
#define WW 256
#define CC 3
#define KK 9
#define OC 64
#define KD 27
#define PSTS 40    // patch/D/S row stride in shorts (80 B) — proven 0-conflict b128 pattern
#define WRB 5120   // per-wave LDS bytes: 64 rows x 80B (D-tail packed in bytes 64..79)
#define XST (4 * WRB)   // xstage offset in LDSBUF = 20480
#define XSLOT 1024      // shorts per staged slot (256 px * 4 shorts)
#define ROWS 2          // output rows per block
#define SLOTS 8         // staged rows: r0-3 .. r0+4

typedef __attribute__((ext_vector_type(8))) short bf16x8;
typedef __attribute__((ext_vector_type(4))) short s16x4;
typedef __attribute__((ext_vector_type(4))) float f32x4;
typedef __attribute__((ext_vector_type(2))) float f32x2;
typedef __attribute__((ext_vector_type(2))) unsigned int u32x2;
typedef __attribute__((ext_vector_type(4))) unsigned int u32x4;

// hardware RNE f32 -> bf16
static __device__ __forceinline__ short f2bf(float f) {
    __hip_bfloat16 h = __float2bfloat16(f);
    return __builtin_bit_cast(short, h);
}
static __device__ __forceinline__ unsigned pack2(short a, short b) {
    return (unsigned)(unsigned short)a | ((unsigned)(unsigned short)b << 16);
}
static __device__ __forceinline__ float bf2f(unsigned w) {   // low 16 bits
    return __uint_as_float(w << 16);
}
static __device__ __forceinline__ float bfup(unsigned w) {   // high 16 bits
    return __uint_as_float(w & 0xffff0000u);
}
static __device__ __forceinline__ unsigned q8(float z) {     // sigmoid -> u8
    float s = 1.0f / (1.0f + __expf(-z));
    return (unsigned)__builtin_rintf(s * 255.0f);
}

// ===================== prep: weight fragments only (1 block, 64 threads) =======
__global__ __launch_bounds__(64) void dcn_prep(
    const float* __restrict__ w_offset, const float* __restrict__ b_offset,
    const float* __restrict__ w_mask,   const float* __restrict__ b_mask,
    const float* __restrict__ w_conv,
    short* __restrict__ wcf, char* __restrict__ wof)
{
    const int tid = threadIdx.x;   // 0..63
    const int fm = tid & 15, kc = tid >> 4;
#pragma unroll
    for (int t = 0; t < 4; ++t) {
        bf16x8 v;
#pragma unroll
        for (int e = 0; e < 8; ++e) {
            int kd = kc * 8 + e;
            v[e] = (kd < KD) ? f2bf(w_conv[(t * 16 + fm) * KD + kd]) : (short)0;
        }
        *(bf16x8*)(wcf + tid * 32 + t * 8) = v;
    }
#pragma unroll
    for (int t = 0; t < 2; ++t) {
        int ch = t * 16 + fm;
        bf16x8 vh, vl;
#pragma unroll
        for (int e = 0; e < 8; ++e) {
            int kd = kc * 8 + e;
            float val = 0.0f;
            if (kd < KD) {
                if (ch < 18) val = w_offset[ch * KD + kd];
                else if (ch < KD) val = w_mask[(ch - 18) * KD + kd];
            }
            unsigned u = __float_as_uint(val);
            vh[e] = (short)(u >> 16);
            float d = val - __uint_as_float(u & 0xffff0000u);
            vl[e] = (short)(__float_as_uint(d) >> 16);
        }
        *(bf16x8*)(wof + tid * 96 + t * 16) = vh;
        *(bf16x8*)(wof + tid * 96 + 32 + t * 16) = vl;
    }
#pragma unroll
    for (int t = 0; t < 2; ++t) {
        f32x4 cb;
#pragma unroll
        for (int r = 0; r < 4; ++r) {
            int ch = t * 16 + kc * 4 + r;
            float v = 0.0f;
            if (ch < 18) v = b_offset[ch];
            else if (ch < KD) v = b_mask[ch - 18];
            cb[r] = v;
        }
        *(f32x4*)(wof + tid * 96 + 64 + t * 16) = cb;
    }
}

// ================================ main =========================================
// One block = 2 consecutive output rows of one image. 36864 B LDS -> 4 blk/CU.
// Phase 0 stages directly from f32 x (hw-cast to bf16) — no xbf intermediate.
__global__ __launch_bounds__(256, 4) void dcn_main(
    const float* __restrict__ x,     // (B,3,256,256) f32
    const short* __restrict__ wcf,
    const char*  __restrict__ wof,
    float* __restrict__ out)         // (B,64,256,256)
{
    __shared__ __align__(16) char LDSBUF[XST + SLOTS * XSLOT * 2];   // 20480+16384=36864

    const int tid = threadIdx.x;
    const int j = tid;
    const int r0 = (blockIdx.x & 127) * ROWS;
    const int b = blockIdx.x >> 7;
    const int lane = tid & 63;
    const int wv = tid >> 6;
    const int fm = lane & 15;
    const int kc = lane >> 4;

    char* wbase = LDSBUF + wv * WRB;
    short* patchS = (short*)wbase;
    short* xs = (short*)(LDSBUF + XST);   // [8 slots][256 px][4 shorts] bf16

    const float* xb = x + (size_t)b * (CC * HH * WW);

    // ---- phase 0: stage rows r0-3 .. r0+4 (clamped) directly from f32 x ----
    {
        float c0[SLOTS], c1[SLOTS], c2[SLOTS];
#pragma unroll
        for (int s = 0; s < SLOTS; ++s) {
            int gr = min(max(r0 - 3 + s, 0), HH - 1);
            const float* rp = xb + (size_t)gr * WW + tid;
            c0[s] = rp[0];
            c1[s] = rp[HH * WW];
            c2[s] = rp[2 * HH * WW];
        }
#pragma unroll
        for (int s = 0; s < SLOTS; ++s) {
            s16x4 v = {f2bf(c0[s]), f2bf(c1[s]), f2bf(c2[s]), 0};
            *(s16x4*)(xs + s * XSLOT + tid * 4) = v;
        }
    }
    __syncthreads();

    // ---- conv W fragments + bias (loaded once) ----
    const char* wl = wof + lane * 96;
    bf16x8 whi0 = *(const bf16x8*)(wl);
    bf16x8 whi1 = *(const bf16x8*)(wl + 16);
    bf16x8 wlo0 = *(const bf16x8*)(wl + 32);
    bf16x8 wlo1 = *(const bf16x8*)(wl + 48);
    f32x4 cb0 = *(const f32x4*)(wl + 64);
    f32x4 cb1 = *(const f32x4*)(wl + 80);
    bf16x8 afrag[4];
#pragma unroll
    for (int t2 = 0; t2 < 4; ++t2) afrag[t2] = *(const bf16x8*)(wcf + lane * 32 + t2 * 8);

    const float* x0p = xb;
    const float* x1p = xb + (size_t)HH * WW;
    const float* x2p = xb + (size_t)2 * HH * WW;

#pragma unroll 1
    for (int d = 0; d < ROWS; ++d) {
        const int ri = r0 + d;

        // ---- patch from LDS (9 b64 reads), zero-padded at image borders ----
        const bool yok0 = (ri - 1) >= 0, yok2 = (ri + 1) < HH;
        const bool xok0 = (j - 1) >= 0, xok2 = (j + 1) < WW;
        s16x4 pr[3][3];
#pragma unroll
        for (int p = 0; p < 3; ++p) {
#pragma unroll
            for (int q = 0; q < 3; ++q) {
                int xx = min(max(j + q - 1, 0), WW - 1);
                pr[p][q] = *(const s16x4*)(xs + (d + p + 2) * XSLOT + xx * 4);
            }
        }
        {
            short* rp = patchS + lane * PSTS;
#pragma unroll
            for (int o = 0; o < 4; ++o) {
                bf16x8 vh;
#pragma unroll
                for (int e = 0; e < 8; ++e) {
                    int kd = o * 8 + e;
                    if (kd < KD) {
                        int c = kd / 9, rem = kd - c * 9, p = rem / 3, q = rem - p * 3;
                        bool ok = (p == 0 ? yok0 : (p == 2 ? yok2 : true)) &&
                                  (q == 0 ? xok0 : (q == 2 ? xok2 : true));
                        vh[e] = ok ? pr[p][q][c] : (short)0;
                    } else {
                        vh[e] = (short)0;
                    }
                }
                *(bf16x8*)(rp + o * 8) = vh;
            }
        }

        // ---- conv MFMA: D[32ch][64px] = (Whi+Wlo)*Phi + bias ----
        f32x4 dacc[4][2];
#pragma unroll
        for (int g = 0; g < 4; ++g) {
            bf16x8 phi = *(const bf16x8*)(patchS + (g * 16 + fm) * PSTS + kc * 8);
            f32x4 a0 = __builtin_amdgcn_mfma_f32_16x16x32_bf16(whi0, phi, cb0, 0, 0, 0);
            a0 = __builtin_amdgcn_mfma_f32_16x16x32_bf16(wlo0, phi, a0, 0, 0, 0);
            f32x4 a1 = __builtin_amdgcn_mfma_f32_16x16x32_bf16(whi1, phi, cb1, 0, 0, 0);
            a1 = __builtin_amdgcn_mfma_f32_16x16x32_bf16(wlo1, phi, a1, 0, 0, 0);
            dacc[g][0] = a0;
            dacc[g][1] = a1;
        }
        // D rows (80 B): 16 f32 dy/dx (k0..7) @0..63; tail @64: dy8dx8 bf16 (4B),
        // m0..m8 u8 @68..76 (sigmoid applied at write time)
#pragma unroll
        for (int g = 0; g < 4; ++g) {
            int r = g * 16 + fm;
            char* dr = wbase + r * 80;
            *(f32x4*)(dr + kc * 16) = dacc[g][0];
            f32x4 a1 = dacc[g][1];
            if (kc == 0) {          // ch16..19 = dy8, dx8, z0, z1
                *(unsigned*)(dr + 64) = pack2(f2bf(a1[0]), f2bf(a1[1]));
                *(unsigned short*)(dr + 68) = (unsigned short)(q8(a1[2]) | (q8(a1[3]) << 8));
            } else if (kc == 1) {   // ch20..23 = z2..z5
                *(unsigned short*)(dr + 70) = (unsigned short)(q8(a1[0]) | (q8(a1[1]) << 8));
                *(unsigned short*)(dr + 72) = (unsigned short)(q8(a1[2]) | (q8(a1[3]) << 8));
            } else if (kc == 2) {   // ch24..26 = z6..z8
                *(unsigned short*)(dr + 74) = (unsigned short)(q8(a1[0]) | (q8(a1[1]) << 8));
                *(unsigned short*)(dr + 76) = (unsigned short)q8(a1[2]);
            }
        }

        // ---- read own D row fully (before S overwrites region) ----
        const char* myD = wbase + lane * 80;
        f32x4 d03 = *(const f32x4*)(myD);
        f32x4 d47 = *(const f32x4*)(myD + 16);
        f32x4 d8b = *(const f32x4*)(myD + 32);
        f32x4 dcf = *(const f32x4*)(myD + 48);
        u32x4 tail = *(const u32x4*)(myD + 64);   // dy8dx8 | m0..m3 | m4..m7 | m8

        const float dyv[9] = {d03[0], d03[2], d47[0], d47[2], d8b[0], d8b[2], dcf[0], dcf[2],
                              bf2f(tail.x)};
        const float dxv[9] = {d03[1], d03[3], d47[1], d47[3], d8b[1], d8b[3], dcf[1], dcf[3],
                              bfup(tail.x)};
        const unsigned mqv[9] = {tail.y & 255u, (tail.y >> 8) & 255u, (tail.y >> 16) & 255u,
                                 tail.y >> 24, tail.z & 255u, (tail.z >> 8) & 255u,
                                 (tail.z >> 16) & 255u, tail.z >> 24, tail.w & 255u};

        // ---- sampling: px-major bf16 LDS reads (fast) with rare global fallback ----
        float s27[KD];
#pragma unroll
        for (int k = 0; k < KK; ++k) {
            float dy = dyv[k], dx = dxv[k];
            float msk = (float)mqv[k] * (1.0f / 255.0f);

            float py = (float)(ri + (k / 3) - 1) + dy;
            float px = (float)(j + (k % 3) - 1) + dx;
            float y0f = floorf(py), x0f = floorf(px);
            float wy = py - y0f, wx = px - x0f;
            int y0 = (int)y0f, x0 = (int)x0f;
            int y1 = y0 + 1, x1 = x0 + 1;

            float w00 = (1.0f - wy) * (1.0f - wx);
            float w01 = (1.0f - wy) * wx;
            float w10 = wy * (1.0f - wx);
            float w11 = wy * wx;

            bool v0y = (unsigned)y0 < HH, v1y = (unsigned)y1 < HH;
            bool v0x = (unsigned)x0 < WW, v1x = (unsigned)x1 < WW;
            float f00 = (v0y && v0x) ? w00 : 0.0f;
            float f01 = (v0y && v1x) ? w01 : 0.0f;
            float f10 = (v1y && v0x) ? w10 : 0.0f;
            float f11 = (v1y && v1x) ? w11 : 0.0f;

            int y0c = min(max(y0, 0), HH - 1), y1c = min(max(y1, 0), HH - 1);
            int s0 = y0c - r0 + 3;       // slot index, valid 0..7
            int s1 = y1c - r0 + 3;
            float r0v_, r1v_, r2v_;
            if (__builtin_expect(__any(((unsigned)s0 > (SLOTS - 1)) ||
                                       ((unsigned)s1 > (SLOTS - 1))), 0)) {
                // ---- slow path: global f32 gather (exact semantics) ----
                int x0c = min(max(x0, 0), WW - 1), x1c = min(max(x1, 0), WW - 1);
                int o00 = y0c * WW + x0c, o01 = y0c * WW + x1c;
                int o10 = y1c * WW + x0c, o11 = y1c * WW + x1c;
                r0v_ = x0p[o00] * f00 + x0p[o01] * f01 + x0p[o10] * f10 + x0p[o11] * f11;
                r1v_ = x1p[o00] * f00 + x1p[o01] * f01 + x1p[o10] * f10 + x1p[o11] * f11;
                r2v_ = x2p[o00] * f00 + x2p[o01] * f01 + x2p[o10] * f10 + x2p[o11] * f11;
            } else {
                // ---- fast path: 4 x 8B LDS reads; clamped-x handled by weight swap ----
                int xl = min(max(x0, 0), WW - 2);
                bool sw = (x0 != xl);
                const short* p0 = xs + s0 * XSLOT + xl * 4;
                const short* p1 = xs + s1 * XSLOT + xl * 4;
                u32x2 lo0 = *(const u32x2*)p0;
                u32x2 hi0 = *(const u32x2*)(p0 + 4);
                u32x2 lo1 = *(const u32x2*)p1;
                u32x2 hi1 = *(const u32x2*)(p1 + 4);

                float a0 = sw ? f01 : f00, b0 = sw ? f00 : f01;
                float a1w = sw ? f11 : f10, b1w = sw ? f10 : f11;

                r0v_ = fmaf(bf2f(lo0.x), a0, fmaf(bf2f(hi0.x), b0,
                       fmaf(bf2f(lo1.x), a1w, bf2f(hi1.x) * b1w)));
                r1v_ = fmaf(bfup(lo0.x), a0, fmaf(bfup(hi0.x), b0,
                       fmaf(bfup(lo1.x), a1w, bfup(hi1.x) * b1w)));
                r2v_ = fmaf(bf2f(lo0.y), a0, fmaf(bf2f(hi0.y), b0,
                       fmaf(bf2f(lo1.y), a1w, bf2f(hi1.y) * b1w)));
            }
            s27[k]      = r0v_ * msk;
            s27[9 + k]  = r1v_ * msk;
            s27[18 + k] = r2v_ * msk;
        }

        // ---- S rows: stride-80 b128 writes ----
        {
            short* srow = patchS + lane * PSTS;
#pragma unroll
            for (int o = 0; o < 4; ++o) {
                bf16x8 v;
#pragma unroll
                for (int e = 0; e < 8; ++e) {
                    int kd = o * 8 + e;
                    v[e] = (kd < KD) ? f2bf(s27[kd]) : (short)0;
                }
                *(bf16x8*)(srow + o * 8) = v;
            }
        }

        // ---- MFMA epilogue, operand-swapped: 4 consecutive px per lane ----
        float* obase = out + ((size_t)b * OC * HH + ri) * WW;
#pragma unroll
        for (int g = 0; g < 4; ++g) {
            bf16x8 sfrag = *(const bf16x8*)(patchS + (g * 16 + fm) * PSTS + kc * 8);
#pragma unroll
            for (int t2 = 0; t2 < 4; ++t2) {
                f32x4 acc = (f32x4){0.f, 0.f, 0.f, 0.f};
                acc = __builtin_amdgcn_mfma_f32_16x16x32_bf16(sfrag, afrag[t2], acc, 0, 0, 0);
                float* op = obase + (size_t)(t2 * 16 + fm) * (HH * WW) + (wv * 64 + g * 16 + kc * 4);
                *(f32x4*)op = acc;
            }
        }
    }
}

extern "C" void kernel_launch(void* const* d_in, const int* in_sizes, int n_in,
                              void* d_out, int out_size, void* d_ws, size_t ws_size,
                              hipStream_t stream) {
    const float* x        = (const float*)d_in[0];
    const float* w_offset = (const float*)d_in[1];
    const float* b_offset = (const float*)d_in[2];
    const float* w_mask   = (const float*)d_in[3];
    const float* b_mask   = (const float*)d_in[4];
    const float* w_conv   = (const float*)d_in[5];
    float* out = (float*)d_out;

    int B = in_sizes[0] / (CC * HH * WW);   // 16

    short* wcf = (short*)d_ws;              // 4096 B
    char*  wof = (char*)d_ws + 4096;        // 6144 B

    hipLaunchKernelGGL(dcn_prep, dim3(1), dim3(64), 0, stream,
                       w_offset, b_offset, w_mask, b_mask, w_conv, wcf, wof);
    hipLaunchKernelGGL(dcn_main, dim3(B * (HH / ROWS)), dim3(256), 0, stream,
                       x, wcf, wof, out);
}